// Round 18
// baseline (72.233 us; speedup 1.0000x reference)
//
#include <hip/hip_runtime.h>
#include <hip/hip_bf16.h>

#define B_  8
#define S_  2048
#define D_  128
#define H_  4
#define HD_ 32
#define BH_ (B_ * H_)

typedef __bf16 bf16x8 __attribute__((ext_vector_type(8)));
typedef float f32x16 __attribute__((ext_vector_type(16)));

__device__ inline bf16x8 ld8(const __hip_bfloat16* p) {
    return *reinterpret_cast<const bf16x8*>(p);
}
__device__ inline unsigned cvtpk(float lo, float hi) {
    unsigned r;
    asm("v_cvt_pk_bf16_f32 %0, %1, %2" : "=v"(r) : "v"(lo), "v"(hi));
    return r;
}
__device__ inline void swap32(unsigned &a, unsigned &b) {
    asm("v_permlane32_swap_b32 %0, %1" : "+v"(a), "+v"(b));
}
__device__ inline float ex2(float x) { return __builtin_amdgcn_exp2f(x); }

// ---------------------------------------------------------------------------
// QKV GEMM with in-block weight staging (r16 validated).
// Block = (mblk, head): 128 m-rows x one head's 96 w-rows (Q,K,V slices).
// ---------------------------------------------------------------------------
__global__ __launch_bounds__(256) void qkv_mfma(const float* __restrict__ x,
                                                const float* __restrict__ wa,
                                                __hip_bfloat16* __restrict__ Qb,
                                                __hip_bfloat16* __restrict__ Kb,
                                                __hip_bfloat16* __restrict__ Vt) {
    __shared__ __align__(16) __hip_bfloat16 wl[96][136];

    const int head = blockIdx.x & 3;
    const int mblk = blockIdx.x >> 2;
    const int tid  = threadIdx.x;

    for (int idx = tid; idx < 128 * 96; idx += 256) {
        const int k = idx / 96;
        const int c = idx - k * 96;
        const int sec = c >> 5, nloc = c & 31;
        wl[c][k] = __float2bfloat16(wa[k * 384 + sec * 128 + head * 32 + nloc]);
    }
    __syncthreads();

    const int wave = tid >> 6;
    const int lane = tid & 63;
    const int lq   = lane & 31;
    const int hi   = lane >> 5;
    const int m0   = mblk * 128 + wave * 32;

    const float* ax = x + (m0 + lq) * 128 + 8 * hi;
    const __hip_bfloat16* bq = &wl[lq][8 * hi];
    const __hip_bfloat16* bk = &wl[32 + lq][8 * hi];
    const __hip_bfloat16* bv = &wl[64 + lq][8 * hi];

    f32x16 aq = {}, ak = {}, av = {};
#pragma unroll
    for (int ks = 0; ks < 8; ++ks) {
        float4 x0 = *reinterpret_cast<const float4*>(ax + 16 * ks);
        float4 x1 = *reinterpret_cast<const float4*>(ax + 16 * ks + 4);
        union { unsigned u[4]; bf16x8 v; } af;
        af.u[0] = cvtpk(x0.x, x0.y); af.u[1] = cvtpk(x0.z, x0.w);
        af.u[2] = cvtpk(x1.x, x1.y); af.u[3] = cvtpk(x1.z, x1.w);
        const bf16x8 wqf = ld8(bq + 16 * ks);
        const bf16x8 wkf = ld8(bk + 16 * ks);
        const bf16x8 wvf = ld8(bv + 16 * ks);
        aq = __builtin_amdgcn_mfma_f32_32x32x16_bf16(wqf, af.v, aq, 0, 0, 0);
        ak = __builtin_amdgcn_mfma_f32_32x32x16_bf16(wkf, af.v, ak, 0, 0, 0);
        av = __builtin_amdgcn_mfma_f32_32x32x16_bf16(af.v, wvf, av, 0, 0, 0);
    }

    const int b  = m0 >> 11;
    const int s0 = m0 & (S_ - 1);
    const int bh = b * H_ + head;
    const float qs = 0.2550052557342824f;         // 1/sqrt(32) * log2(e)

    __hip_bfloat16* qrow = Qb + (bh * S_ + s0 + lq) * HD_ + 4 * hi;
    __hip_bfloat16* krow = Kb + (bh * S_ + s0 + lq) * HD_ + 4 * hi;
#pragma unroll
    for (int g = 0; g < 4; ++g) {
        union { __hip_bfloat16 h[4]; ushort4 u; } pq, pk;
#pragma unroll
        for (int j = 0; j < 4; ++j) {
            pq.h[j] = __float2bfloat16(aq[4 * g + j] * qs);
            pk.h[j] = __float2bfloat16(ak[4 * g + j]);
        }
        *reinterpret_cast<ushort4*>(qrow + 8 * g) = pq.u;
        *reinterpret_cast<ushort4*>(krow + 8 * g) = pk.u;
    }
    __hip_bfloat16* vbase = Vt + (bh * HD_ + lq) * S_ + s0;
#pragma unroll
    for (int g = 0; g < 4; ++g) {
        union { __hip_bfloat16 h[4]; ushort4 u; } pv;
#pragma unroll
        for (int j = 0; j < 4; ++j) pv.h[j] = __float2bfloat16(av[4 * g + j]);
        *reinterpret_cast<ushort4*>(vbase + 8 * g + 4 * hi) = pv.u;
    }
}

// ---------------------------------------------------------------------------
// Flash attention, 64-q blocks + T15 two-tile pipeline: wave steps k by 8,
// processing tiles (t, t+4) per iteration into SEPARATE accumulators
// (independent MFMA->exp->pack->MFMA chains interleave on MFMA/VALU pipes).
// Fixed-offset softmax -> partials merge by plain addition. Generalized
// causal mask (kloc > lq + 32*(diag - t)) covers diagonal + phantom tiles.
// ---------------------------------------------------------------------------
__global__ __launch_bounds__(256, 3) void fattn_kernel(
    const __hip_bfloat16* __restrict__ Qb,
    const __hip_bfloat16* __restrict__ Kb,
    const __hip_bfloat16* __restrict__ Vt,
    __hip_bfloat16* __restrict__ AOb)
{
    __shared__ float Ol[4][64][33];
    __shared__ float Ll[4][64];

    const int bh   = blockIdx.x & 31;             // head -> stable XCD
    const int qt2  = 31 - (blockIdx.x >> 5);      // longest first
    const int tid  = threadIdx.x;
    const int wv   = tid >> 6;
    const int lane = tid & 63;
    const int lq   = lane & 31;
    const int hi   = lane >> 5;

    const int q0  = qt2 * 64;
    const int qtA = 2 * qt2;
    const int qtB = qtA + 1;
    const int nt  = qtB + 1;

    const __hip_bfloat16* qrowA = Qb + (bh * S_ + q0 + lq) * HD_ + 8 * hi;
    const __hip_bfloat16* qrowB = qrowA + 32 * HD_;
    const bf16x8 qfA0 = ld8(qrowA), qfA1 = ld8(qrowA + 16);
    const bf16x8 qfB0 = ld8(qrowB), qfB1 = ld8(qrowB + 16);

    const __hip_bfloat16* kp = Kb + bh * S_ * HD_ + lq * HD_ + 8 * hi;
    const __hip_bfloat16* vp = Vt + (bh * HD_ + lq) * S_ + 8 * hi;

    f32x16 oA1 = {}, oA2 = {}, oB1 = {}, oB2 = {};
    float lA1 = 0.f, lA2 = 0.f, lB1 = 0.f, lB2 = 0.f;

    // 1-deep prefetch for the even slot
    bf16x8 kA0 = {}, kA1 = {}, vA0 = {}, vA1 = {};
    if (wv < nt) {
        kA0 = ld8(kp + wv * 32 * HD_); kA1 = ld8(kp + wv * 32 * HD_ + 16);
        vA0 = ld8(vp + wv * 32);       vA1 = ld8(vp + wv * 32 + 16);
    }

#define TILEWORK(T, QF0, QF1, DT, CK0, CK1, CV0, CV1, OACC, LS)                 \
    {                                                                           \
        __builtin_amdgcn_s_setprio(1);                                          \
        f32x16 s = {};                                                          \
        s = __builtin_amdgcn_mfma_f32_32x32x16_bf16(CK0, QF0, s, 0, 0, 0);      \
        s = __builtin_amdgcn_mfma_f32_32x32x16_bf16(CK1, QF1, s, 0, 0, 0);      \
        __builtin_amdgcn_s_setprio(0);                                          \
        if ((T) >= (DT)) {                                                      \
            const int lim = lq + (((DT) - (T)) << 5);                           \
            _Pragma("unroll")                                                   \
            for (int r = 0; r < 16; ++r) {                                      \
                const int kloc = (r & 3) + 8 * (r >> 2) + 4 * hi;               \
                s[r] = (kloc > lim) ? -1e30f : s[r];                            \
            }                                                                   \
        }                                                                       \
        _Pragma("unroll")                                                       \
        for (int r = 0; r < 16; ++r) s[r] = ex2(s[r]);                          \
        {                                                                       \
            float p0 = (s[0] + s[1]) + (s[2] + s[3]);                           \
            float p1 = (s[4] + s[5]) + (s[6] + s[7]);                           \
            float p2 = (s[8] + s[9]) + (s[10] + s[11]);                         \
            float p3 = (s[12] + s[13]) + (s[14] + s[15]);                       \
            LS += (p0 + p1) + (p2 + p3);                                        \
        }                                                                       \
        unsigned a0 = cvtpk(s[0], s[1]),   a1 = cvtpk(s[2], s[3]);              \
        unsigned a2 = cvtpk(s[4], s[5]),   a3 = cvtpk(s[6], s[7]);              \
        swap32(a0, a2); swap32(a1, a3);                                         \
        unsigned b0 = cvtpk(s[8], s[9]),   b1 = cvtpk(s[10], s[11]);            \
        unsigned b2 = cvtpk(s[12], s[13]), b3 = cvtpk(s[14], s[15]);            \
        swap32(b0, b2); swap32(b1, b3);                                         \
        union { unsigned u[4]; bf16x8 v; } pb0, pb1;                            \
        pb0.u[0] = a0; pb0.u[1] = a1; pb0.u[2] = a2; pb0.u[3] = a3;             \
        pb1.u[0] = b0; pb1.u[1] = b1; pb1.u[2] = b2; pb1.u[3] = b3;             \
        __builtin_amdgcn_s_setprio(1);                                          \
        OACC = __builtin_amdgcn_mfma_f32_32x32x16_bf16(CV0, pb0.v, OACC, 0, 0, 0); \
        OACC = __builtin_amdgcn_mfma_f32_32x32x16_bf16(CV1, pb1.v, OACC, 0, 0, 0); \
        __builtin_amdgcn_s_setprio(0);                                          \
    }

    for (int t = wv; t < nt; t += 8) {
        const bf16x8 cka0 = kA0, cka1 = kA1, cva0 = vA0, cva1 = vA1;
        const bool odd = (t + 4 < nt);

        bf16x8 ckb0 = {}, ckb1 = {}, cvb0 = {}, cvb1 = {};
        if (odd) {                                 // odd-slot loads, issued early
            const __hip_bfloat16* kn = kp + (t + 4) * 32 * HD_;
            const __hip_bfloat16* vn = vp + (t + 4) * 32;
            ckb0 = ld8(kn); ckb1 = ld8(kn + 16);
            cvb0 = ld8(vn); cvb1 = ld8(vn + 16);
        }
        if (t + 8 < nt) {                          // prefetch next even slot
            const __hip_bfloat16* kn = kp + (t + 8) * 32 * HD_;
            const __hip_bfloat16* vn = vp + (t + 8) * 32;
            kA0 = ld8(kn); kA1 = ld8(kn + 16);
            vA0 = ld8(vn); vA1 = ld8(vn + 16);
        }

        TILEWORK(t, qfA0, qfA1, qtA, cka0, cka1, cva0, cva1, oA1, lA1)
        if (odd) TILEWORK(t + 4, qfA0, qfA1, qtA, ckb0, ckb1, cvb0, cvb1, oA2, lA2)
        TILEWORK(t, qfB0, qfB1, qtB, cka0, cka1, cva0, cva1, oB1, lB1)
        if (odd) TILEWORK(t + 4, qfB0, qfB1, qtB, ckb0, ckb1, cvb0, cvb1, oB2, lB2)
    }
#undef TILEWORK

    float lsumA = lA1 + lA2;
    float lsumB = lB1 + lB2;
    lsumA += __shfl_xor(lsumA, 32);
    lsumB += __shfl_xor(lsumB, 32);

#pragma unroll
    for (int r = 0; r < 16; ++r) {
        const int d = (r & 3) + 8 * (r >> 2) + 4 * hi;
        Ol[wv][lq][d]      = oA1[r] + oA2[r];
        Ol[wv][32 + lq][d] = oB1[r] + oB2[r];
    }
    if (hi == 0) { Ll[wv][lq] = lsumA; Ll[wv][32 + lq] = lsumB; }
    __syncthreads();

    const int q  = tid >> 2;                      // 0..63
    const int d0 = (tid & 3) * 8;                 // 0,8,16,24
    const float lst = Ll[0][q] + Ll[1][q] + Ll[2][q] + Ll[3][q];
    const float inv = 1.f / lst;

    const int b = bh >> 2, h = bh & 3;
    __hip_bfloat16* orow = AOb + (b * S_ + q0 + q) * D_ + h * HD_ + d0;
#pragma unroll
    for (int g = 0; g < 2; ++g) {
        union { __hip_bfloat16 h4[4]; ushort4 u; } st;
#pragma unroll
        for (int j = 0; j < 4; ++j) {
            const int d = d0 + 4 * g + j;
            const float o = Ol[0][q][d] + Ol[1][q][d] + Ol[2][q][d] + Ol[3][q][d];
            st.h4[j] = __float2bfloat16(o * inv);
        }
        *reinterpret_cast<ushort4*>(orow + 4 * g) = st.u;
    }
}

// ---------------------------------------------------------------------------
// Projection GEMM with in-block weight staging (r16 validated).
// [16384,128]x[128,128] -> fp32. Swapped operands -> 4x float4 stores.
// ---------------------------------------------------------------------------
__global__ __launch_bounds__(256) void proj_mfma(const __hip_bfloat16* __restrict__ AOb,
                                                 const float* __restrict__ wp,
                                                 float* __restrict__ out) {
    __shared__ __align__(16) __hip_bfloat16 wl[128][136];

    const int tid = threadIdx.x;
    for (int idx = tid; idx < 128 * 128; idx += 256) {
        const int k = idx >> 7, n = idx & 127;
        wl[n][k] = __float2bfloat16(wp[idx]);
    }
    __syncthreads();

    const int m0   = blockIdx.x * 32;
    const int wave = tid >> 6;
    const int lane = tid & 63;
    const int lq   = lane & 31;
    const int hi   = lane >> 5;
    const int n0   = wave * 32;

    const __hip_bfloat16* ap = AOb + (m0 + lq) * 128 + 8 * hi;
    const __hip_bfloat16* bp = &wl[n0 + lq][8 * hi];

    f32x16 acc = {};
#pragma unroll
    for (int ks = 0; ks < 8; ++ks) {
        const bf16x8 af = ld8(ap + 16 * ks);
        const bf16x8 bf = ld8(bp + 16 * ks);
        acc = __builtin_amdgcn_mfma_f32_32x32x16_bf16(bf, af, acc, 0, 0, 0);
    }

    float* orow = out + (m0 + lq) * 128 + n0 + 4 * hi;
#pragma unroll
    for (int g = 0; g < 4; ++g) {
        float4 st = make_float4(acc[4 * g], acc[4 * g + 1], acc[4 * g + 2], acc[4 * g + 3]);
        *reinterpret_cast<float4*>(orow + 8 * g) = st;
    }
}

// ---------------------------------------------------------------------------
extern "C" void kernel_launch(void* const* d_in, const int* in_sizes, int n_in,
                              void* d_out, int out_size, void* d_ws, size_t ws_size,
                              hipStream_t stream) {
    const float* x      = (const float*)d_in[0];
    const float* w_attn = (const float*)d_in[1];
    const float* w_proj = (const float*)d_in[2];
    float* out = (float*)d_out;

    char* ws = (char*)d_ws;
    __hip_bfloat16* Qb  = (__hip_bfloat16*)(ws);                     // 4 MB
    __hip_bfloat16* Kb  = (__hip_bfloat16*)(ws + (4  << 20));        // 4 MB
    __hip_bfloat16* Vt  = (__hip_bfloat16*)(ws + (8  << 20));        // 4 MB
    __hip_bfloat16* AOb = (__hip_bfloat16*)(ws + (12 << 20));        // 4 MB

    qkv_mfma<<<512, 256, 0, stream>>>(x, w_attn, Qb, Kb, Vt);
    fattn_kernel<<<BH_ * 32, 256, 0, stream>>>(Qb, Kb, Vt, AOb);
    proj_mfma<<<512, 256, 0, stream>>>(AOb, w_proj, out);
}

// Round 19
// 42.756 us; speedup vs baseline: 1.6894x; 1.6894x over previous
//
#include <hip/hip_runtime.h>
#include <hip/hip_bf16.h>

#define B_  8
#define S_  2048
#define D_  128
#define H_  4
#define HD_ 32
#define BH_ (B_ * H_)

typedef __bf16 bf16x8 __attribute__((ext_vector_type(8)));
typedef float f32x16 __attribute__((ext_vector_type(16)));

__device__ inline bf16x8 ld8(const __hip_bfloat16* p) {
    return *reinterpret_cast<const bf16x8*>(p);
}
__device__ inline unsigned cvtpk(float lo, float hi) {
    unsigned r;
    asm("v_cvt_pk_bf16_f32 %0, %1, %2" : "=v"(r) : "v"(lo), "v"(hi));
    return r;
}
__device__ inline void swap32(unsigned &a, unsigned &b) {
    asm("v_permlane32_swap_b32 %0, %1" : "+v"(a), "+v"(b));
}
__device__ inline float ex2(float x) { return __builtin_amdgcn_exp2f(x); }

// ---------------------------------------------------------------------------
// QKV GEMM with in-block weight staging (r16 validated), now emitting K and V
// in MFMA-FRAGMENT-LINEAR layout:
//   Xf[bh][tile][frag][l][e] : frag load in fattn = base + lane*16B (1KB dense)
// where Xf[...][f][l][e] = X[tile*32 + (l&31)][f*16 + (l>>5)*8 + e]
// (for K: second index is hd; for V: roles of s/hd swapped -> same formula).
// Q stays row-major [bh][S][HD] (already perfectly coalesced in fattn).
// ---------------------------------------------------------------------------
__global__ __launch_bounds__(256) void qkv_mfma(const float* __restrict__ x,
                                                const float* __restrict__ wa,
                                                __hip_bfloat16* __restrict__ Qb,
                                                __hip_bfloat16* __restrict__ Kf,
                                                __hip_bfloat16* __restrict__ Vf) {
    __shared__ __align__(16) __hip_bfloat16 wl[96][136];

    const int head = blockIdx.x & 3;
    const int mblk = blockIdx.x >> 2;
    const int tid  = threadIdx.x;

    for (int idx = tid; idx < 128 * 96; idx += 256) {
        const int k = idx / 96;
        const int c = idx - k * 96;
        const int sec = c >> 5, nloc = c & 31;
        wl[c][k] = __float2bfloat16(wa[k * 384 + sec * 128 + head * 32 + nloc]);
    }
    __syncthreads();

    const int wave = tid >> 6;
    const int lane = tid & 63;
    const int lq   = lane & 31;
    const int hi   = lane >> 5;
    const int m0   = mblk * 128 + wave * 32;

    const float* ax = x + (m0 + lq) * 128 + 8 * hi;
    const __hip_bfloat16* bq = &wl[lq][8 * hi];
    const __hip_bfloat16* bk = &wl[32 + lq][8 * hi];
    const __hip_bfloat16* bv = &wl[64 + lq][8 * hi];

    f32x16 aq = {}, ak = {}, av = {};
#pragma unroll
    for (int ks = 0; ks < 8; ++ks) {
        float4 x0 = *reinterpret_cast<const float4*>(ax + 16 * ks);
        float4 x1 = *reinterpret_cast<const float4*>(ax + 16 * ks + 4);
        union { unsigned u[4]; bf16x8 v; } af;
        af.u[0] = cvtpk(x0.x, x0.y); af.u[1] = cvtpk(x0.z, x0.w);
        af.u[2] = cvtpk(x1.x, x1.y); af.u[3] = cvtpk(x1.z, x1.w);
        const bf16x8 wqf = ld8(bq + 16 * ks);
        const bf16x8 wkf = ld8(bk + 16 * ks);
        const bf16x8 wvf = ld8(bv + 16 * ks);
        // Q/K swapped (lane = m-row): thread holds X[s0+lq][hd=8g+4hi+j]
        aq = __builtin_amdgcn_mfma_f32_32x32x16_bf16(wqf, af.v, aq, 0, 0, 0);
        ak = __builtin_amdgcn_mfma_f32_32x32x16_bf16(wkf, af.v, ak, 0, 0, 0);
        // V normal (lane = hd): thread holds V[s0+8g+4hi+j][hd=lq]
        av = __builtin_amdgcn_mfma_f32_32x32x16_bf16(af.v, wvf, av, 0, 0, 0);
    }

    const int b  = m0 >> 11;
    const int s0 = m0 & (S_ - 1);
    const int bh = b * H_ + head;
    const int t  = s0 >> 5;                       // k-tile index within bh
    const float qs = 0.2550052557342824f;         // 1/sqrt(32) * log2(e)

    __hip_bfloat16* qrow = Qb + (bh * S_ + s0 + lq) * HD_ + 4 * hi;
    __hip_bfloat16* kfb  = Kf + ((bh * 64 + t) << 10);   // 1024 elems per tile
    __hip_bfloat16* vfb  = Vf + ((bh * 64 + t) << 10);
#pragma unroll
    for (int g = 0; g < 4; ++g) {
        union { __hip_bfloat16 h[4]; ushort4 u; } pq, pk, pv;
#pragma unroll
        for (int j = 0; j < 4; ++j) {
            pq.h[j] = __float2bfloat16(aq[4 * g + j] * qs);
            pk.h[j] = __float2bfloat16(ak[4 * g + j]);
            pv.h[j] = __float2bfloat16(av[4 * g + j]);
        }
        *reinterpret_cast<ushort4*>(qrow + 8 * g) = pq.u;
        // fragment-linear: elem offset = f*512 + l*8 + e0,
        // f = g>>1, l = (g&1)*32 + lq, e0 = 4*hi   (same formula for K and V)
        const int off = ((g >> 1) << 9) + ((((g & 1) << 5) + lq) << 3) + 4 * hi;
        *reinterpret_cast<ushort4*>(kfb + off) = pk.u;
        *reinterpret_cast<ushort4*>(vfb + off) = pv.u;
    }
}

// ---------------------------------------------------------------------------
// Flash attention, 64-q blocks (r14/r16 validated body). K/V fragment loads
// are now single dense 1KB-per-wave reads from the fragment-linear buffers:
// frag f of tile t at lane l:  Xf + bh*65536 + t*1024 + f*512 + l*8.
// 4-way k-split, 1-deep prefetch, zero-offset softmax, longest-first.
// ---------------------------------------------------------------------------
__global__ __launch_bounds__(256, 4) void fattn_kernel(
    const __hip_bfloat16* __restrict__ Qb,
    const __hip_bfloat16* __restrict__ Kf,
    const __hip_bfloat16* __restrict__ Vf,
    __hip_bfloat16* __restrict__ AOb)
{
    __shared__ float Ol[4][64][33];
    __shared__ float Ll[4][64];

    const int bh   = blockIdx.x & 31;             // head -> stable XCD
    const int qt2  = 31 - (blockIdx.x >> 5);      // 0..31, longest first
    const int tid  = threadIdx.x;
    const int wv   = tid >> 6;
    const int lane = tid & 63;
    const int lq   = lane & 31;
    const int hi   = lane >> 5;

    const int q0  = qt2 * 64;
    const int qtA = 2 * qt2;
    const int qtB = qtA + 1;
    const int nt  = qtB + 1;

    const __hip_bfloat16* qrowA = Qb + (bh * S_ + q0 + lq) * HD_ + 8 * hi;
    const __hip_bfloat16* qrowB = qrowA + 32 * HD_;
    const bf16x8 qfA0 = ld8(qrowA), qfA1 = ld8(qrowA + 16);
    const bf16x8 qfB0 = ld8(qrowB), qfB1 = ld8(qrowB + 16);

    const __hip_bfloat16* kp = Kf + (bh << 16) + lane * 8;
    const __hip_bfloat16* vp = Vf + (bh << 16) + lane * 8;

    f32x16 oaccA = {}, oaccB = {};
    float lsumA = 0.f, lsumB = 0.f;

    bf16x8 k0a = {}, k1a = {}, v0a = {}, v1a = {};
    if (wv < nt) {
        k0a = ld8(kp + wv * 1024); k1a = ld8(kp + wv * 1024 + 512);
        v0a = ld8(vp + wv * 1024); v1a = ld8(vp + wv * 1024 + 512);
    }

    for (int t = wv; t < nt; t += 4) {
        const bf16x8 ck0 = k0a, ck1 = k1a, cv0 = v0a, cv1 = v1a;
        if (t + 4 < nt) {
            k0a = ld8(kp + (t + 4) * 1024); k1a = ld8(kp + (t + 4) * 1024 + 512);
            v0a = ld8(vp + (t + 4) * 1024); v1a = ld8(vp + (t + 4) * 1024 + 512);
        }

        if (t <= qtA) {
            __builtin_amdgcn_s_setprio(1);
            f32x16 s = {};
            s = __builtin_amdgcn_mfma_f32_32x32x16_bf16(ck0, qfA0, s, 0, 0, 0);
            s = __builtin_amdgcn_mfma_f32_32x32x16_bf16(ck1, qfA1, s, 0, 0, 0);
            __builtin_amdgcn_s_setprio(0);

            if (t == qtA) {
#pragma unroll
                for (int r = 0; r < 16; ++r) {
                    const int kloc = (r & 3) + 8 * (r >> 2) + 4 * hi;
                    s[r] = (kloc > lq) ? -1e30f : s[r];
                }
            }
#pragma unroll
            for (int r = 0; r < 16; ++r) s[r] = ex2(s[r]);
            {
                float p0 = (s[0] + s[1]) + (s[2] + s[3]);
                float p1 = (s[4] + s[5]) + (s[6] + s[7]);
                float p2 = (s[8] + s[9]) + (s[10] + s[11]);
                float p3 = (s[12] + s[13]) + (s[14] + s[15]);
                lsumA += (p0 + p1) + (p2 + p3);
            }
            unsigned a0 = cvtpk(s[0], s[1]),   a1 = cvtpk(s[2], s[3]);
            unsigned a2 = cvtpk(s[4], s[5]),   a3 = cvtpk(s[6], s[7]);
            swap32(a0, a2); swap32(a1, a3);
            unsigned b0 = cvtpk(s[8], s[9]),   b1 = cvtpk(s[10], s[11]);
            unsigned b2 = cvtpk(s[12], s[13]), b3 = cvtpk(s[14], s[15]);
            swap32(b0, b2); swap32(b1, b3);
            union { unsigned u[4]; bf16x8 v; } pb0, pb1;
            pb0.u[0] = a0; pb0.u[1] = a1; pb0.u[2] = a2; pb0.u[3] = a3;
            pb1.u[0] = b0; pb1.u[1] = b1; pb1.u[2] = b2; pb1.u[3] = b3;

            __builtin_amdgcn_s_setprio(1);
            oaccA = __builtin_amdgcn_mfma_f32_32x32x16_bf16(cv0, pb0.v, oaccA, 0, 0, 0);
            oaccA = __builtin_amdgcn_mfma_f32_32x32x16_bf16(cv1, pb1.v, oaccA, 0, 0, 0);
            __builtin_amdgcn_s_setprio(0);
        }

        {
            __builtin_amdgcn_s_setprio(1);
            f32x16 s = {};
            s = __builtin_amdgcn_mfma_f32_32x32x16_bf16(ck0, qfB0, s, 0, 0, 0);
            s = __builtin_amdgcn_mfma_f32_32x32x16_bf16(ck1, qfB1, s, 0, 0, 0);
            __builtin_amdgcn_s_setprio(0);

            if (t == qtB) {
#pragma unroll
                for (int r = 0; r < 16; ++r) {
                    const int kloc = (r & 3) + 8 * (r >> 2) + 4 * hi;
                    s[r] = (kloc > lq) ? -1e30f : s[r];
                }
            }
#pragma unroll
            for (int r = 0; r < 16; ++r) s[r] = ex2(s[r]);
            {
                float p0 = (s[0] + s[1]) + (s[2] + s[3]);
                float p1 = (s[4] + s[5]) + (s[6] + s[7]);
                float p2 = (s[8] + s[9]) + (s[10] + s[11]);
                float p3 = (s[12] + s[13]) + (s[14] + s[15]);
                lsumB += (p0 + p1) + (p2 + p3);
            }
            unsigned a0 = cvtpk(s[0], s[1]),   a1 = cvtpk(s[2], s[3]);
            unsigned a2 = cvtpk(s[4], s[5]),   a3 = cvtpk(s[6], s[7]);
            swap32(a0, a2); swap32(a1, a3);
            unsigned b0 = cvtpk(s[8], s[9]),   b1 = cvtpk(s[10], s[11]);
            unsigned b2 = cvtpk(s[12], s[13]), b3 = cvtpk(s[14], s[15]);
            swap32(b0, b2); swap32(b1, b3);
            union { unsigned u[4]; bf16x8 v; } pb0, pb1;
            pb0.u[0] = a0; pb0.u[1] = a1; pb0.u[2] = a2; pb0.u[3] = a3;
            pb1.u[0] = b0; pb1.u[1] = b1; pb1.u[2] = b2; pb1.u[3] = b3;

            __builtin_amdgcn_s_setprio(1);
            oaccB = __builtin_amdgcn_mfma_f32_32x32x16_bf16(cv0, pb0.v, oaccB, 0, 0, 0);
            oaccB = __builtin_amdgcn_mfma_f32_32x32x16_bf16(cv1, pb1.v, oaccB, 0, 0, 0);
            __builtin_amdgcn_s_setprio(0);
        }
    }

    lsumA += __shfl_xor(lsumA, 32);
    lsumB += __shfl_xor(lsumB, 32);

#pragma unroll
    for (int r = 0; r < 16; ++r) {
        const int d = (r & 3) + 8 * (r >> 2) + 4 * hi;
        Ol[wv][lq][d]      = oaccA[r];
        Ol[wv][32 + lq][d] = oaccB[r];
    }
    if (hi == 0) { Ll[wv][lq] = lsumA; Ll[wv][32 + lq] = lsumB; }
    __syncthreads();

    const int q  = tid >> 2;                      // 0..63
    const int d0 = (tid & 3) * 8;                 // 0,8,16,24
    const float lst = Ll[0][q] + Ll[1][q] + Ll[2][q] + Ll[3][q];
    const float inv = 1.f / lst;

    const int b = bh >> 2, h = bh & 3;
    __hip_bfloat16* orow = AOb + (b * S_ + q0 + q) * D_ + h * HD_ + d0;
#pragma unroll
    for (int g = 0; g < 2; ++g) {
        union { __hip_bfloat16 h4[4]; ushort4 u; } st;
#pragma unroll
        for (int j = 0; j < 4; ++j) {
            const int d = d0 + 4 * g + j;
            const float o = Ol[0][q][d] + Ol[1][q][d] + Ol[2][q][d] + Ol[3][q][d];
            st.h4[j] = __float2bfloat16(o * inv);
        }
        *reinterpret_cast<ushort4*>(orow + 4 * g) = st.u;
    }
}

// ---------------------------------------------------------------------------
// Projection GEMM with in-block weight staging (r16 validated).
// [16384,128]x[128,128] -> fp32. Swapped operands -> 4x float4 stores.
// ---------------------------------------------------------------------------
__global__ __launch_bounds__(256) void proj_mfma(const __hip_bfloat16* __restrict__ AOb,
                                                 const float* __restrict__ wp,
                                                 float* __restrict__ out) {
    __shared__ __align__(16) __hip_bfloat16 wl[128][136];

    const int tid = threadIdx.x;
    for (int idx = tid; idx < 128 * 128; idx += 256) {
        const int k = idx >> 7, n = idx & 127;
        wl[n][k] = __float2bfloat16(wp[idx]);
    }
    __syncthreads();

    const int m0   = blockIdx.x * 32;
    const int wave = tid >> 6;
    const int lane = tid & 63;
    const int lq   = lane & 31;
    const int hi   = lane >> 5;
    const int n0   = wave * 32;

    const __hip_bfloat16* ap = AOb + (m0 + lq) * 128 + 8 * hi;
    const __hip_bfloat16* bp = &wl[n0 + lq][8 * hi];

    f32x16 acc = {};
#pragma unroll
    for (int ks = 0; ks < 8; ++ks) {
        const bf16x8 af = ld8(ap + 16 * ks);
        const bf16x8 bf = ld8(bp + 16 * ks);
        acc = __builtin_amdgcn_mfma_f32_32x32x16_bf16(bf, af, acc, 0, 0, 0);
    }

    float* orow = out + (m0 + lq) * 128 + n0 + 4 * hi;
#pragma unroll
    for (int g = 0; g < 4; ++g) {
        float4 st = make_float4(acc[4 * g], acc[4 * g + 1], acc[4 * g + 2], acc[4 * g + 3]);
        *reinterpret_cast<float4*>(orow + 8 * g) = st;
    }
}

// ---------------------------------------------------------------------------
extern "C" void kernel_launch(void* const* d_in, const int* in_sizes, int n_in,
                              void* d_out, int out_size, void* d_ws, size_t ws_size,
                              hipStream_t stream) {
    const float* x      = (const float*)d_in[0];
    const float* w_attn = (const float*)d_in[1];
    const float* w_proj = (const float*)d_in[2];
    float* out = (float*)d_out;

    char* ws = (char*)d_ws;
    __hip_bfloat16* Qb  = (__hip_bfloat16*)(ws);                     // 4 MB
    __hip_bfloat16* Kf  = (__hip_bfloat16*)(ws + (4  << 20));        // 4 MB
    __hip_bfloat16* Vf  = (__hip_bfloat16*)(ws + (8  << 20));        // 4 MB
    __hip_bfloat16* AOb = (__hip_bfloat16*)(ws + (12 << 20));        // 4 MB

    qkv_mfma<<<512, 256, 0, stream>>>(x, w_attn, Qb, Kf, Vf);
    fattn_kernel<<<BH_ * 32, 256, 0, stream>>>(Qb, Kf, Vf, AOb);
    proj_mfma<<<512, 256, 0, stream>>>(AOb, w_proj, out);
}